// Round 1
// baseline (255.571 us; speedup 1.0000x reference)
//
#include <hip/hip_runtime.h>
#include <math.h>

#define NS 68
#define NSP 69            // padded LDS row stride: 69 % 32 = 5, coprime w/ 32 -> conflict-free
#define ROWS 128          // rows per block == threads per block
#define F4_PER_ROW 17     // 68 / 4
#define F4_PER_BLOCK (ROWS * F4_PER_ROW)
#define EPSC 1e-10f

__global__ __launch_bounds__(ROWS) void MAPKPI3KODE_rhs_kernel(
    const float* __restrict__ y,
    const float* __restrict__ params,
    float* __restrict__ out)
{
    __shared__ float sm[ROWS * NSP];   // 128 * 69 * 4 = 35328 B
    const int t = threadIdx.x;
    const int base4 = blockIdx.x * F4_PER_BLOCK;

    // ---- stage in: coalesced float4 loads, scatter to padded LDS ----
    const float4* __restrict__ y4 = (const float4*)y;
    #pragma unroll
    for (int k = 0; k < F4_PER_ROW; ++k) {
        int g = k * ROWS + t;                 // float4 index within block tile
        float4 v = y4[base4 + g];
        int row = g / F4_PER_ROW;             // float4s never straddle rows (17 per row)
        int c4  = g - row * F4_PER_ROW;
        float* dst = &sm[row * NSP + 4 * c4];
        dst[0] = v.x; dst[1] = v.y; dst[2] = v.z; dst[3] = v.w;
    }
    __syncthreads();

    // ---- per-thread row: Y = clip(y, 0) ----
    float Y[NS];
    {
        const float* my = &sm[t * NSP];
        #pragma unroll
        for (int i = 0; i < NS; ++i) Y[i] = fmaxf(my[i], 0.0f);
    }

    // ---- params (uniform; compiler scalarizes) ----
    const float ka1             = params[0];
    const float kr1             = params[1];
    const float kc1             = params[2];
    const float kpCraf          = params[3];
    const float kpMek           = params[4];
    const float kpErk           = params[5];
    const float kDegradEgfr     = params[6];
    const float kErkInbEgfr     = params[7];
    const float kShcDephos      = params[8];
    const float kptpDeg         = params[9];
    const float kGrb2CombShc    = params[10];
    const float kSprtyInbGrb2   = params[11];
    const float kSosCombGrb2    = params[12];
    const float kErkPhosSos     = params[13];
    const float kErkPhosPcraf   = params[14];
    const float kPcrafDegrad    = params[15];
    const float kErkPhosMek     = params[16];
    const float kMekDegrad      = params[17];
    const float kDuspInbErk     = params[18];
    const float kErkDeg         = params[19];
    const float kinbBraf        = params[20];
    const float kDuspStop       = params[21];
    const float kDusps          = params[22];
    const float kSproutyForm    = params[23];
    const float kSprtyComeDown  = params[24];
    const float kdegrad         = params[25];
    // params[26] km_Sprty_decay unused
    const float km_Dusp         = params[27];
    const float km_Sprty        = params[28];
    const float kErkDephos      = params[29];
    const float kDuspDeg        = params[30];
    const float kHer2_act       = params[31];
    const float kHer3_act       = params[32];
    const float k_p85_bind_EGFR = params[33];
    const float k_p85_bind_Her2 = params[34];
    const float k_p85_bind_Her3 = params[35];
    const float k_p85_bind_IGFR = params[36];
    const float k_p85_unbind    = params[37];
    const float k_PI3K_recruit  = params[38];
    const float kMTOR_Feedback  = params[39];
    const float k_PIP2_to_PIP3  = params[40];
    const float k_PTEN          = params[41];
    const float kAkt            = params[42];
    const float kdegradAKT      = params[43];
    const float kb1             = params[44];
    const float k43b1           = params[45];
    const float k4ebp1          = params[46];
    const float k_4EBP1_dephos  = params[47];
    const float kKSRphos        = params[48];
    const float kKSRdephos      = params[49];
    const float kMekByBraf      = params[50];
    const float kMekByCraf      = params[51];
    const float kMekByKSR       = params[52];
    const float Tram            = params[53];
    // params[54] K_tram_RAF unused
    const float K_tram_KSR      = params[55];
    const float n_tram          = params[56];
    const float Vemurafenib     = params[57];
    const float kDimerForm      = params[58];
    const float kDimerDissoc    = params[59];
    const float kParadoxCRAF    = params[60];
    const float IC50_vem        = params[61];
    const float Hill_n_vem      = params[62];
    const float kPDGFR_act      = params[63];
    const float k_p85_bind_PDGFR= params[64];
    const float kS6K_phos       = params[65];
    const float kS6K_dephos     = params[66];
    const float kRAS_PI3K       = params[67];
    const float kERK_IRS_inhibit   = params[68];
    const float kERK_PTEN_activate = params[69];
    const float kAKT_CRAF_inhibit  = params[70];
    const float kS6K_IRS_inhibit   = params[71];
    const float kERK_GAB1_inhibit  = params[72];
    const float kAKT_TSC2_phos     = params[73];
    const float kERK_RSK_activate  = params[74];

    // uniform precomputes
    const float IC50_n   = powf(IC50_vem, Hill_n_vem);
    const float Vem_n    = powf(Vemurafenib, Hill_n_vem);
    const float kBRAF_eff = ka1 * IC50_n / (IC50_n + Vem_n + EPSC);
    const float Ktram_n  = powf(K_tram_KSR, n_tram);
    const float tram_n   = powf(Tram, n_tram);
    const float tram_ksr = Ktram_n / (Ktram_n + tram_n + EPSC);

    float d[NS];

    // --- EGFR / Her2 / Her3 receptor modules ---
    d[0] = -ka1*Y[0] + kr1*Y[1];
    d[1] =  ka1*Y[0] - kr1*Y[1] - kc1*Y[1];
    d[2] =  kc1*Y[1] - kDegradEgfr*Y[2] - kErkInbEgfr*Y[28]*Y[2];
    d[3] = -kHer2_act*Y[3] + kr1*Y[4];
    d[4] =  kHer2_act*Y[3] - kr1*Y[4] - kc1*Y[4];
    d[5] =  kc1*Y[4] - kDegradEgfr*Y[5] - kErkInbEgfr*Y[28]*Y[5];
    d[6] = -kHer3_act*Y[6] + kr1*Y[7];
    d[7] =  kHer3_act*Y[6] - kr1*Y[7] - kc1*Y[7];
    d[8] =  kc1*Y[7] - kDegradEgfr*Y[8] - kErkInbEgfr*Y[28]*Y[8];
    // --- Shc / Grb2 / Sos / Ras ---
    d[9]  = -ka1*Y[2]*Y[9];
    d[10] =  ka1*Y[2]*Y[9] - kShcDephos*Y[11]*Y[10];
    d[11] = -kptpDeg*Y[10]*Y[11];
    d[12] =  kGrb2CombShc*Y[10]*Y[2] - kSprtyInbGrb2*Y[26]*Y[12];
    d[13] =  kSosCombGrb2*Y[12]*Y[10] - kErkPhosSos*Y[24]*Y[13];
    d[14] = -ka1*Y[13]*Y[14];
    d[15] =  ka1*Y[13]*Y[14];
    d[16] = -ka1*Y[13]*Y[16];
    d[17] =  ka1*Y[13]*Y[16];
    d[18] = -ka1*Y[13]*Y[18];
    d[19] =  ka1*Y[13]*Y[18] - ka1*Y[19]*Y[20];
    d[20] = -ka1*Y[19]*Y[20];
    // --- RAF with vemurafenib paradox ---
    {
        const float paradox = kParadoxCRAF * Vemurafenib * Y[61];
        const float akt_inh_craf = kAKT_CRAF_inhibit * Y[52] * Y[21];
        const float dimf = kDimerForm * Y[24] * Y[21] * Vemurafenib;
        const float dimd = kDimerDissoc * Y[61];
        d[21] = -kpCraf*Y[19]*Y[21] + kErkPhosPcraf*Y[28]*Y[22]
                + kPcrafDegrad*Y[22]*Y[35]
                - dimf + dimd - akt_inh_craf;
        d[22] =  kpCraf*Y[19]*Y[21] - kErkPhosPcraf*Y[28]*Y[22]
                - kPcrafDegrad*Y[22]*Y[35] + paradox;
        d[23] = -kBRAF_eff*Y[23]*Y[19] - dimf + dimd;
        d[24] =  kBRAF_eff*Y[23]*Y[19] - kinbBraf*Y[24] - dimf + dimd;
        d[61] =  dimf - dimd - kPcrafDegrad*Y[61]*Y[35];
    }
    // --- MEK / ERK ---
    {
        const float raf_to_mek = kpMek*Y[22] + kMekByBraf*Y[24] + kMekByCraf*Y[22];
        const float ksr_to_mek = kMekByKSR*Y[60];
        const float to_mek = (raf_to_mek + ksr_to_mek) * Y[25];
        d[25] = -to_mek + kErkPhosMek*Y[28]*Y[26] + kMekDegrad*Y[26]*Y[34];
        d[26] =  to_mek - kErkPhosMek*Y[28]*Y[26] - kMekDegrad*Y[26]*Y[34];
        d[27] = -kpErk*Y[26]*Y[27] + kDuspInbErk*Y[30]*Y[28]
                + kErkDeg*Y[28]*Y[33] + kErkDephos*Y[30]*Y[28];
        d[28] =  kpErk*Y[26]*Y[27] - kDuspInbErk*Y[30]*Y[28]
                - kErkDeg*Y[28]*Y[33] - kErkDephos*Y[30]*Y[28];
    }
    // --- DUSP / Sprouty feedback ---
    {
        const float denom_dusp = 1.0f + km_Dusp / (kDusps + EPSC) * Y[28];
        d[29] = km_Dusp*Y[28]/(denom_dusp + EPSC) - kDuspStop*Y[29]*Y[36] - kDuspDeg*Y[29]*Y[28];
        d[30] = -kDuspStop*Y[29]*Y[30];
        const float denom_spry = 1.0f + km_Sprty / (kSproutyForm + EPSC) * Y[28];
        d[31] = km_Sprty*Y[28]/(denom_spry + EPSC) - kSprtyComeDown*Y[31]*Y[32];
        d[32] = -kSprtyComeDown*Y[31]*Y[32];
        d[33] = -kErkDeg*Y[28]*Y[33];
        d[34] = -kMekDegrad*Y[26]*Y[34];
        d[35] = -kPcrafDegrad*Y[22]*Y[35];
        d[36] = -kDuspStop*Y[29]*Y[36];
    }
    // --- IGFR / IRS ---
    d[37] = -ka1*Y[37] + kr1*Y[38];
    d[38] =  ka1*Y[37] - kr1*Y[38] - kc1*Y[38];
    d[39] =  kc1*Y[38] - kErkInbEgfr*Y[28]*Y[39];
    {
        const float erk_irs = kERK_IRS_inhibit*Y[28]*Y[41];
        const float s6k_irs = kS6K_IRS_inhibit*Y[66]*Y[41];
        d[40] = -ka1*Y[2]*Y[40] + erk_irs + s6k_irs;
        d[41] =  ka1*Y[2]*Y[40] - erk_irs - s6k_irs;
    }
    // --- p85 binding ---
    {
        const float gab1 = 1.0f / (1.0f + kERK_GAB1_inhibit*Y[28]);
        const float bE = k_p85_bind_EGFR*Y[2]*Y[42]*gab1;
        const float b2 = k_p85_bind_Her2*Y[5]*Y[42]*gab1;
        const float b3 = k_p85_bind_Her3*Y[8]*Y[42]*gab1;
        const float bI = k_p85_bind_IGFR*Y[39]*Y[42];
        const float bP = k_p85_bind_PDGFR*Y[64]*Y[42];
        const float total_p85c = Y[43] + Y[44] + Y[45] + Y[46] + Y[67];
        d[42] = -bE - b2 - b3 - bI - bP + k_p85_unbind*total_p85c;
        d[43] = bE - k_p85_unbind*Y[43];
        d[44] = b2 - k_p85_unbind*Y[44];
        d[45] = b3 - k_p85_unbind*Y[45];
        d[46] = bI - k_p85_unbind*Y[46];
        d[67] = bP - k_p85_unbind*Y[67];
        // --- PI3K/AKT/mTOR axis ---
        const float pi3k_act = k_PI3K_recruit*total_p85c*Y[47] + kRAS_PI3K*Y[15]*Y[47];
        const float mtor_fb  = kMTOR_Feedback*Y[56]*Y[48];
        d[47] = -pi3k_act + mtor_fb;
        d[48] =  pi3k_act - mtor_fb;
    }
    d[49] = -k_PIP2_to_PIP3*Y[48]*Y[49] + k_PTEN*Y[51]*Y[50];
    d[50] =  k_PIP2_to_PIP3*Y[48]*Y[49] - k_PTEN*Y[51]*Y[50];
    d[51] =  kERK_PTEN_activate*Y[28] - kdegrad*Y[51];
    d[52] =  kAkt*Y[50]*Y[53] - kdegradAKT*Y[52];
    d[53] = -kAkt*Y[50]*Y[53] + kdegradAKT*Y[52];
    d[54] = -kAKT_TSC2_phos*Y[52]*Y[54];
    d[55] =  kAKT_TSC2_phos*Y[52]*Y[54] - kdegrad*Y[55];
    d[56] =  kb1*Y[52]*Y[57] - k43b1*Y[56];
    d[57] = -kb1*Y[52]*Y[57] + k43b1*Y[56];
    d[58] = -k4ebp1*Y[56]*Y[58] + k_4EBP1_dephos*Y[59];
    d[59] =  k4ebp1*Y[56]*Y[58] - k_4EBP1_dephos*Y[59];
    // --- KSR with trametinib hill factor ---
    d[60] =  kKSRphos*Y[19]*Y[62]*tram_ksr - kKSRdephos*Y[60];
    d[62] = -kKSRphos*Y[19]*Y[62]*tram_ksr + kKSRdephos*Y[60];
    // --- PDGFR ---
    d[63] = -kPDGFR_act*Y[63];
    d[64] =  kPDGFR_act*Y[63] - kDegradEgfr*Y[64];
    // --- S6K ---
    d[65] = -kS6K_phos*Y[56]*Y[65] + kS6K_dephos*Y[66] - kERK_RSK_activate*Y[28]*Y[65];
    d[66] =  kS6K_phos*Y[56]*Y[65] - kS6K_dephos*Y[66] + kERK_RSK_activate*Y[28]*Y[65];

    // ---- write results to own LDS row (thread-private region; no barrier needed
    //      before this — each thread only ever touches its own padded row here) ----
    {
        float* my = &sm[t * NSP];
        #pragma unroll
        for (int i = 0; i < NS; ++i) my[i] = d[i];
    }
    __syncthreads();   // other threads' d must land before coalesced gather below

    // ---- stage out: gather from padded LDS, coalesced float4 stores ----
    float4* __restrict__ out4 = (float4*)out;
    #pragma unroll
    for (int k = 0; k < F4_PER_ROW; ++k) {
        int g = k * ROWS + t;
        int row = g / F4_PER_ROW;
        int c4  = g - row * F4_PER_ROW;
        const float* src = &sm[row * NSP + 4 * c4];
        float4 v;
        v.x = src[0]; v.y = src[1]; v.z = src[2]; v.w = src[3];
        out4[base4 + g] = v;
    }
}

extern "C" void kernel_launch(void* const* d_in, const int* in_sizes, int n_in,
                              void* d_out, int out_size, void* d_ws, size_t ws_size,
                              hipStream_t stream) {
    // setup_inputs order: t (1,), y (B*68,), params (75,)
    const float* y      = (const float*)d_in[1];
    const float* params = (const float*)d_in[2];
    float* out          = (float*)d_out;

    const int rows   = in_sizes[1] / NS;   // B = 524288
    const int blocks = rows / ROWS;        // 4096 (divides exactly)

    MAPKPI3KODE_rhs_kernel<<<blocks, ROWS, 0, stream>>>(y, params, out);
}

// Round 2
// 254.672 us; speedup vs baseline: 1.0035x; 1.0035x over previous
//
#include <hip/hip_runtime.h>
#include <math.h>

#define NS 68
#define NSP 69            // padded LDS row stride: 69 % 32 = 5, coprime w/ 32 -> 2-way max on b32
#define BLOCK 128         // 2 waves per block
#define WAVE 64
#define F4_PER_ROW 17     // 68 / 4
#define F4_PER_WAVE (WAVE * F4_PER_ROW)   // 1088 float4 per wave tile
#define EPSC 1e-10f

// Per-WAVE private LDS tile => no __syncthreads anywhere. A CDNA wave is
// lockstep (one PC), so ds_write -> ds_read ordering within the wave is
// guaranteed by the compiler's lgkmcnt waits. Waves free-run independently,
// so memory latency of one wave overlaps compute of another with no barrier
// coupling. Global access stays perfectly coalesced (float4, lane-consecutive).
__global__ __launch_bounds__(BLOCK) void MAPKPI3KODE_rhs_kernel(
    const float* __restrict__ y,
    const float* __restrict__ params,
    float* __restrict__ out)
{
    __shared__ float sm[(BLOCK / WAVE) * WAVE * NSP];   // 2 * 64 * 69 * 4 = 35328 B
    const int t    = threadIdx.x;
    const int wid  = t >> 6;          // wave id within block
    const int lane = t & 63;
    float* wsm = &sm[wid * WAVE * NSP];

    // global float4 base for this wave's 64-row tile
    const int wave_base4 = (blockIdx.x * (BLOCK / WAVE) + wid) * F4_PER_WAVE;

    // ---- stage in: coalesced float4 loads, scatter to padded per-wave LDS ----
    const float4* __restrict__ y4 = (const float4*)y;
    #pragma unroll
    for (int k = 0; k < F4_PER_ROW; ++k) {
        int g = k * WAVE + lane;              // float4 index within wave tile
        float4 v = y4[wave_base4 + g];
        int row = g / F4_PER_ROW;             // float4s never straddle rows (17 per row)
        int c4  = g - row * F4_PER_ROW;
        float* dst = &wsm[row * NSP + 4 * c4];
        dst[0] = v.x; dst[1] = v.y; dst[2] = v.z; dst[3] = v.w;
    }
    // no barrier: wave-private tile, lockstep wave, lgkmcnt handles ordering

    // ---- per-thread row: Y = clip(y, 0) ----
    float Y[NS];
    {
        const float* my = &wsm[lane * NSP];
        #pragma unroll
        for (int i = 0; i < NS; ++i) Y[i] = fmaxf(my[i], 0.0f);
    }

    // ---- params (uniform; compiler scalarizes) ----
    const float ka1             = params[0];
    const float kr1             = params[1];
    const float kc1             = params[2];
    const float kpCraf          = params[3];
    const float kpMek           = params[4];
    const float kpErk           = params[5];
    const float kDegradEgfr     = params[6];
    const float kErkInbEgfr     = params[7];
    const float kShcDephos      = params[8];
    const float kptpDeg         = params[9];
    const float kGrb2CombShc    = params[10];
    const float kSprtyInbGrb2   = params[11];
    const float kSosCombGrb2    = params[12];
    const float kErkPhosSos     = params[13];
    const float kErkPhosPcraf   = params[14];
    const float kPcrafDegrad    = params[15];
    const float kErkPhosMek     = params[16];
    const float kMekDegrad      = params[17];
    const float kDuspInbErk     = params[18];
    const float kErkDeg         = params[19];
    const float kinbBraf        = params[20];
    const float kDuspStop       = params[21];
    const float kDusps          = params[22];
    const float kSproutyForm    = params[23];
    const float kSprtyComeDown  = params[24];
    const float kdegrad         = params[25];
    // params[26] km_Sprty_decay unused
    const float km_Dusp         = params[27];
    const float km_Sprty        = params[28];
    const float kErkDephos      = params[29];
    const float kDuspDeg        = params[30];
    const float kHer2_act       = params[31];
    const float kHer3_act       = params[32];
    const float k_p85_bind_EGFR = params[33];
    const float k_p85_bind_Her2 = params[34];
    const float k_p85_bind_Her3 = params[35];
    const float k_p85_bind_IGFR = params[36];
    const float k_p85_unbind    = params[37];
    const float k_PI3K_recruit  = params[38];
    const float kMTOR_Feedback  = params[39];
    const float k_PIP2_to_PIP3  = params[40];
    const float k_PTEN          = params[41];
    const float kAkt            = params[42];
    const float kdegradAKT      = params[43];
    const float kb1             = params[44];
    const float k43b1           = params[45];
    const float k4ebp1          = params[46];
    const float k_4EBP1_dephos  = params[47];
    const float kKSRphos        = params[48];
    const float kKSRdephos      = params[49];
    const float kMekByBraf      = params[50];
    const float kMekByCraf      = params[51];
    const float kMekByKSR       = params[52];
    const float Tram            = params[53];
    // params[54] K_tram_RAF unused
    const float K_tram_KSR      = params[55];
    const float n_tram          = params[56];
    const float Vemurafenib     = params[57];
    const float kDimerForm      = params[58];
    const float kDimerDissoc    = params[59];
    const float kParadoxCRAF    = params[60];
    const float IC50_vem        = params[61];
    const float Hill_n_vem      = params[62];
    const float kPDGFR_act      = params[63];
    const float k_p85_bind_PDGFR= params[64];
    const float kS6K_phos       = params[65];
    const float kS6K_dephos     = params[66];
    const float kRAS_PI3K       = params[67];
    const float kERK_IRS_inhibit   = params[68];
    const float kERK_PTEN_activate = params[69];
    const float kAKT_CRAF_inhibit  = params[70];
    const float kS6K_IRS_inhibit   = params[71];
    const float kERK_GAB1_inhibit  = params[72];
    const float kAKT_TSC2_phos     = params[73];
    const float kERK_RSK_activate  = params[74];

    // uniform precomputes
    const float IC50_n   = powf(IC50_vem, Hill_n_vem);
    const float Vem_n    = powf(Vemurafenib, Hill_n_vem);
    const float kBRAF_eff = ka1 * IC50_n / (IC50_n + Vem_n + EPSC);
    const float Ktram_n  = powf(K_tram_KSR, n_tram);
    const float tram_n   = powf(Tram, n_tram);
    const float tram_ksr = Ktram_n / (Ktram_n + tram_n + EPSC);

    float d[NS];

    // --- EGFR / Her2 / Her3 receptor modules ---
    d[0] = -ka1*Y[0] + kr1*Y[1];
    d[1] =  ka1*Y[0] - kr1*Y[1] - kc1*Y[1];
    d[2] =  kc1*Y[1] - kDegradEgfr*Y[2] - kErkInbEgfr*Y[28]*Y[2];
    d[3] = -kHer2_act*Y[3] + kr1*Y[4];
    d[4] =  kHer2_act*Y[3] - kr1*Y[4] - kc1*Y[4];
    d[5] =  kc1*Y[4] - kDegradEgfr*Y[5] - kErkInbEgfr*Y[28]*Y[5];
    d[6] = -kHer3_act*Y[6] + kr1*Y[7];
    d[7] =  kHer3_act*Y[6] - kr1*Y[7] - kc1*Y[7];
    d[8] =  kc1*Y[7] - kDegradEgfr*Y[8] - kErkInbEgfr*Y[28]*Y[8];
    // --- Shc / Grb2 / Sos / Ras ---
    d[9]  = -ka1*Y[2]*Y[9];
    d[10] =  ka1*Y[2]*Y[9] - kShcDephos*Y[11]*Y[10];
    d[11] = -kptpDeg*Y[10]*Y[11];
    d[12] =  kGrb2CombShc*Y[10]*Y[2] - kSprtyInbGrb2*Y[26]*Y[12];
    d[13] =  kSosCombGrb2*Y[12]*Y[10] - kErkPhosSos*Y[24]*Y[13];
    d[14] = -ka1*Y[13]*Y[14];
    d[15] =  ka1*Y[13]*Y[14];
    d[16] = -ka1*Y[13]*Y[16];
    d[17] =  ka1*Y[13]*Y[16];
    d[18] = -ka1*Y[13]*Y[18];
    d[19] =  ka1*Y[13]*Y[18] - ka1*Y[19]*Y[20];
    d[20] = -ka1*Y[19]*Y[20];
    // --- RAF with vemurafenib paradox ---
    {
        const float paradox = kParadoxCRAF * Vemurafenib * Y[61];
        const float akt_inh_craf = kAKT_CRAF_inhibit * Y[52] * Y[21];
        const float dimf = kDimerForm * Y[24] * Y[21] * Vemurafenib;
        const float dimd = kDimerDissoc * Y[61];
        d[21] = -kpCraf*Y[19]*Y[21] + kErkPhosPcraf*Y[28]*Y[22]
                + kPcrafDegrad*Y[22]*Y[35]
                - dimf + dimd - akt_inh_craf;
        d[22] =  kpCraf*Y[19]*Y[21] - kErkPhosPcraf*Y[28]*Y[22]
                - kPcrafDegrad*Y[22]*Y[35] + paradox;
        d[23] = -kBRAF_eff*Y[23]*Y[19] - dimf + dimd;
        d[24] =  kBRAF_eff*Y[23]*Y[19] - kinbBraf*Y[24] - dimf + dimd;
        d[61] =  dimf - dimd - kPcrafDegrad*Y[61]*Y[35];
    }
    // --- MEK / ERK ---
    {
        const float raf_to_mek = kpMek*Y[22] + kMekByBraf*Y[24] + kMekByCraf*Y[22];
        const float ksr_to_mek = kMekByKSR*Y[60];
        const float to_mek = (raf_to_mek + ksr_to_mek) * Y[25];
        d[25] = -to_mek + kErkPhosMek*Y[28]*Y[26] + kMekDegrad*Y[26]*Y[34];
        d[26] =  to_mek - kErkPhosMek*Y[28]*Y[26] - kMekDegrad*Y[26]*Y[34];
        d[27] = -kpErk*Y[26]*Y[27] + kDuspInbErk*Y[30]*Y[28]
                + kErkDeg*Y[28]*Y[33] + kErkDephos*Y[30]*Y[28];
        d[28] =  kpErk*Y[26]*Y[27] - kDuspInbErk*Y[30]*Y[28]
                - kErkDeg*Y[28]*Y[33] - kErkDephos*Y[30]*Y[28];
    }
    // --- DUSP / Sprouty feedback ---
    {
        const float denom_dusp = 1.0f + km_Dusp / (kDusps + EPSC) * Y[28];
        d[29] = km_Dusp*Y[28]/(denom_dusp + EPSC) - kDuspStop*Y[29]*Y[36] - kDuspDeg*Y[29]*Y[28];
        d[30] = -kDuspStop*Y[29]*Y[30];
        const float denom_spry = 1.0f + km_Sprty / (kSproutyForm + EPSC) * Y[28];
        d[31] = km_Sprty*Y[28]/(denom_spry + EPSC) - kSprtyComeDown*Y[31]*Y[32];
        d[32] = -kSprtyComeDown*Y[31]*Y[32];
        d[33] = -kErkDeg*Y[28]*Y[33];
        d[34] = -kMekDegrad*Y[26]*Y[34];
        d[35] = -kPcrafDegrad*Y[22]*Y[35];
        d[36] = -kDuspStop*Y[29]*Y[36];
    }
    // --- IGFR / IRS ---
    d[37] = -ka1*Y[37] + kr1*Y[38];
    d[38] =  ka1*Y[37] - kr1*Y[38] - kc1*Y[38];
    d[39] =  kc1*Y[38] - kErkInbEgfr*Y[28]*Y[39];
    {
        const float erk_irs = kERK_IRS_inhibit*Y[28]*Y[41];
        const float s6k_irs = kS6K_IRS_inhibit*Y[66]*Y[41];
        d[40] = -ka1*Y[2]*Y[40] + erk_irs + s6k_irs;
        d[41] =  ka1*Y[2]*Y[40] - erk_irs - s6k_irs;
    }
    // --- p85 binding ---
    {
        const float gab1 = 1.0f / (1.0f + kERK_GAB1_inhibit*Y[28]);
        const float bE = k_p85_bind_EGFR*Y[2]*Y[42]*gab1;
        const float b2 = k_p85_bind_Her2*Y[5]*Y[42]*gab1;
        const float b3 = k_p85_bind_Her3*Y[8]*Y[42]*gab1;
        const float bI = k_p85_bind_IGFR*Y[39]*Y[42];
        const float bP = k_p85_bind_PDGFR*Y[64]*Y[42];
        const float total_p85c = Y[43] + Y[44] + Y[45] + Y[46] + Y[67];
        d[42] = -bE - b2 - b3 - bI - bP + k_p85_unbind*total_p85c;
        d[43] = bE - k_p85_unbind*Y[43];
        d[44] = b2 - k_p85_unbind*Y[44];
        d[45] = b3 - k_p85_unbind*Y[45];
        d[46] = bI - k_p85_unbind*Y[46];
        d[67] = bP - k_p85_unbind*Y[67];
        // --- PI3K/AKT/mTOR axis ---
        const float pi3k_act = k_PI3K_recruit*total_p85c*Y[47] + kRAS_PI3K*Y[15]*Y[47];
        const float mtor_fb  = kMTOR_Feedback*Y[56]*Y[48];
        d[47] = -pi3k_act + mtor_fb;
        d[48] =  pi3k_act - mtor_fb;
    }
    d[49] = -k_PIP2_to_PIP3*Y[48]*Y[49] + k_PTEN*Y[51]*Y[50];
    d[50] =  k_PIP2_to_PIP3*Y[48]*Y[49] - k_PTEN*Y[51]*Y[50];
    d[51] =  kERK_PTEN_activate*Y[28] - kdegrad*Y[51];
    d[52] =  kAkt*Y[50]*Y[53] - kdegradAKT*Y[52];
    d[53] = -kAkt*Y[50]*Y[53] + kdegradAKT*Y[52];
    d[54] = -kAKT_TSC2_phos*Y[52]*Y[54];
    d[55] =  kAKT_TSC2_phos*Y[52]*Y[54] - kdegrad*Y[55];
    d[56] =  kb1*Y[52]*Y[57] - k43b1*Y[56];
    d[57] = -kb1*Y[52]*Y[57] + k43b1*Y[56];
    d[58] = -k4ebp1*Y[56]*Y[58] + k_4EBP1_dephos*Y[59];
    d[59] =  k4ebp1*Y[56]*Y[58] - k_4EBP1_dephos*Y[59];
    // --- KSR with trametinib hill factor ---
    d[60] =  kKSRphos*Y[19]*Y[62]*tram_ksr - kKSRdephos*Y[60];
    d[62] = -kKSRphos*Y[19]*Y[62]*tram_ksr + kKSRdephos*Y[60];
    // --- PDGFR ---
    d[63] = -kPDGFR_act*Y[63];
    d[64] =  kPDGFR_act*Y[63] - kDegradEgfr*Y[64];
    // --- S6K ---
    d[65] = -kS6K_phos*Y[56]*Y[65] + kS6K_dephos*Y[66] - kERK_RSK_activate*Y[28]*Y[65];
    d[66] =  kS6K_phos*Y[56]*Y[65] - kS6K_dephos*Y[66] + kERK_RSK_activate*Y[28]*Y[65];

    // ---- write results to own LDS row (no barrier: wave-private tile, and the
    //      lockstep wave has executed ALL lanes' writes before any lane's gather) ----
    {
        float* my = &wsm[lane * NSP];
        #pragma unroll
        for (int i = 0; i < NS; ++i) my[i] = d[i];
    }

    // ---- stage out: gather from padded per-wave LDS, coalesced float4 stores ----
    float4* __restrict__ out4 = (float4*)out;
    #pragma unroll
    for (int k = 0; k < F4_PER_ROW; ++k) {
        int g = k * WAVE + lane;
        int row = g / F4_PER_ROW;
        int c4  = g - row * F4_PER_ROW;
        const float* src = &wsm[row * NSP + 4 * c4];
        float4 v;
        v.x = src[0]; v.y = src[1]; v.z = src[2]; v.w = src[3];
        out4[wave_base4 + g] = v;
    }
}

extern "C" void kernel_launch(void* const* d_in, const int* in_sizes, int n_in,
                              void* d_out, int out_size, void* d_ws, size_t ws_size,
                              hipStream_t stream) {
    // setup_inputs order: t (1,), y (B*68,), params (75,)
    const float* y      = (const float*)d_in[1];
    const float* params = (const float*)d_in[2];
    float* out          = (float*)d_out;

    const int rows   = in_sizes[1] / NS;   // B = 524288
    const int blocks = rows / BLOCK;       // 4096 (divides exactly)

    MAPKPI3KODE_rhs_kernel<<<blocks, BLOCK, 0, stream>>>(y, params, out);
}